// Round 3
// baseline (6188.918 us; speedup 1.0000x reference)
//
#include <hip/hip_runtime.h>
#include <hip/hip_bf16.h>

#define NN 50000
#define NE 1600000
#define DD 128

__device__ __forceinline__ float bf2f(unsigned short u) {
    union { unsigned int i; float f; } c; c.i = ((unsigned int)u) << 16; return c.f;
}
__device__ __forceinline__ unsigned short f2bf(float f) {
    __hip_bfloat16 h = __float2bfloat16(f);
    union { __hip_bfloat16 h; unsigned short u; } c; c.h = h; return c.u;
}
// exponent-sanity: true bf16 activations/weights (|v| < 2^15, finite) always pass;
// f32 mantissa-halves are ~uniform 16-bit patterns and fail w.p. ~0.45/sample
__device__ __forceinline__ int insane_bf16(unsigned short u) {
    unsigned e = (u >> 7) & 0xFF;
    return (e == 0xFF) || (e >= 0x8E);
}

// flags[0] = indices are int64; flags[1] = feat is f32; flags[2] = W is f32
__global__ void k_detect(const int* __restrict__ srcw, const int* __restrict__ dstw,
                         const unsigned short* __restrict__ feat16,
                         const unsigned short* __restrict__ w16,
                         int* __restrict__ flags) {
    __shared__ int s_idx, s_feat, s_w;
    int tid = threadIdx.x;
    if (tid == 0) { s_idx = 0; s_feat = 0; s_w = 0; }
    __syncthreads();
    if (tid < 64) {                       // odd 32-bit words of first 32 int64s
        int v = srcw[2 * tid + 1] | dstw[2 * tid + 1];
        if (v) atomicOr(&s_idx, 1);
    }
    if (insane_bf16(feat16[2 * tid]) || insane_bf16(feat16[2 * tid + 512]))
        atomicOr(&s_feat, 1);
    if (insane_bf16(w16[2 * tid]) || insane_bf16(w16[2 * tid + 512]))
        atomicOr(&s_w, 1);
    __syncthreads();
    if (tid == 0) {
        flags[0] = (s_idx == 0) ? 1 : 0;
        flags[1] = s_feat;
        flags[2] = s_w;
    }
}

__device__ __forceinline__ int load_idx(const void* p, int e, int is64) {
    long long v = is64 ? ((const long long*)p)[e] : (long long)((const int*)p)[e];
    int i = (int)v;
    return (i < 0) ? 0 : (i >= NN ? NN - 1 : i);   // safety clamp
}

__global__ void k_zero(float* __restrict__ Y, int* __restrict__ deg) {
    int i = blockIdx.x * 256 + threadIdx.x;
    if (i < NN * DD) Y[i] = 0.0f;
    if (i < NN) deg[i] = 0;
}

__global__ void k_degree(const void* __restrict__ dst, int* __restrict__ deg,
                         const int* __restrict__ flags) {
    int e = blockIdx.x * 256 + threadIdx.x;
    if (e >= NE) return;
    atomicAdd(&deg[load_idx(dst, e, flags[0])], 1);
}

__global__ void k_norm(const int* __restrict__ deg, float* __restrict__ norm) {
    int n = blockIdx.x * 256 + threadIdx.x;
    if (n >= NN) return;
    norm[n] = rsqrtf(fmaxf((float)deg[n], 1.0f));
}

// X[n,d] = feat[n,d] * norm[n]  (X stored bf16), 4 elems/thread
__global__ void k_prescale(const void* __restrict__ feat,
                           const float* __restrict__ norm,
                           unsigned short* __restrict__ X,
                           const int* __restrict__ flags) {
    int i = blockIdx.x * 256 + threadIdx.x;     // quad index
    if (i >= NN * DD / 4) return;
    float nm = norm[i >> 5];
    float4 v;
    if (flags[1]) {
        v = ((const float4*)feat)[i];
    } else {
        ushort4 f = ((const ushort4*)feat)[i];
        v.x = bf2f(f.x); v.y = bf2f(f.y); v.z = bf2f(f.z); v.w = bf2f(f.w);
    }
    ushort4 o;
    o.x = f2bf(v.x * nm); o.y = f2bf(v.y * nm);
    o.z = f2bf(v.z * nm); o.w = f2bf(v.w * nm);
    ((ushort4*)X)[i] = o;
}

// Y[dst] += X[src]; 32 lanes per edge, 4 elems (8B bf16 read, 4 f32 atomics) per lane
__global__ __launch_bounds__(256) void k_scatter(const unsigned short* __restrict__ X,
        const void* __restrict__ src, const void* __restrict__ dst,
        float* __restrict__ Y, const int* __restrict__ flags) {
    int t = blockIdx.x * 256 + threadIdx.x;
    int e = t >> 5;
    if (e >= NE) return;
    int c = (t & 31) << 2;
    int is64 = flags[0];
    int s = load_idx(src, e, is64);
    int d = load_idx(dst, e, is64);
    ushort4 xv = *(const ushort4*)(X + s * DD + c);
    float* yp = Y + d * DD + c;
    unsafeAtomicAdd(yp + 0, bf2f(xv.x));
    unsafeAtomicAdd(yp + 1, bf2f(xv.y));
    unsafeAtomicAdd(yp + 2, bf2f(xv.z));
    unsafeAtomicAdd(yp + 3, bf2f(xv.w));
}

// X = bf16(Y * norm^2) (post-scale hop1 + pre-scale hop2); Y cleared for hop2
__global__ void k_mid(float* __restrict__ Y, unsigned short* __restrict__ X,
                      const float* __restrict__ norm) {
    int i = blockIdx.x * 256 + threadIdx.x;     // quad index
    if (i >= NN * DD / 4) return;
    float nm = norm[i >> 5];
    float n2 = nm * nm;
    float4 v = ((float4*)Y)[i];
    ushort4 o;
    o.x = f2bf(v.x * n2); o.y = f2bf(v.y * n2);
    o.z = f2bf(v.z * n2); o.w = f2bf(v.w * n2);
    ((ushort4*)X)[i] = o;
    ((float4*)Y)[i] = make_float4(0.f, 0.f, 0.f, 0.f);
}

// out[n,o] = (Y[n,:]*norm[n]) . W[o,:] + b[o]
// Output dtype ADAPTIVE: f32 if feat was f32 (flags[1]), else bf16.
#define TM 32
#define TO 64
__global__ __launch_bounds__(256) void k_gemm(const float* __restrict__ Y,
        const float* __restrict__ norm, const void* __restrict__ Wp,
        const void* __restrict__ bp, void* __restrict__ outp,
        const int* __restrict__ flags) {
    __shared__ __align__(16) float Wt[DD * TO];   // [d][ol] 32 KB
    __shared__ float Fl[TM * 129];                // padded rows
    int tid = threadIdx.x;
    int nodeBase = blockIdx.x * TM;
    int obase = blockIdx.y * TO;
    int wf32 = flags[2];
    int of32 = flags[1];

    for (int k = tid; k < DD * TO; k += 256) {
        int d = k >> 6, ol = k & 63;
        int src_i = (obase + ol) * DD + d;
        Wt[d * TO + ol] = wf32 ? ((const float*)Wp)[src_i]
                               : bf2f(((const unsigned short*)Wp)[src_i]);
    }
    for (int k = tid; k < TM * DD; k += 256) {
        int nl = k >> 7, d = k & 127;
        int n = nodeBase + nl;
        float v = (n < NN) ? Y[n * DD + d] * norm[n] : 0.0f;
        Fl[nl * 129 + d] = v;
    }
    __syncthreads();

    int og = tid & 15;   int o0 = og * 4;
    int ng = tid >> 4;   int nl0 = ng * 2;
    float acc00 = 0.f, acc01 = 0.f, acc02 = 0.f, acc03 = 0.f;
    float acc10 = 0.f, acc11 = 0.f, acc12 = 0.f, acc13 = 0.f;
    #pragma unroll 8
    for (int d = 0; d < DD; ++d) {
        float4 w = *(const float4*)&Wt[d * TO + o0];
        float f0 = Fl[nl0 * 129 + d];
        float f1 = Fl[(nl0 + 1) * 129 + d];
        acc00 += f0 * w.x; acc01 += f0 * w.y; acc02 += f0 * w.z; acc03 += f0 * w.w;
        acc10 += f1 * w.x; acc11 += f1 * w.y; acc12 += f1 * w.z; acc13 += f1 * w.w;
    }
    float bias[4];
    #pragma unroll
    for (int j = 0; j < 4; ++j) {
        int bi = obase + o0 + j;
        bias[j] = wf32 ? ((const float*)bp)[bi] : bf2f(((const unsigned short*)bp)[bi]);
    }
    float r0[4] = {acc00 + bias[0], acc01 + bias[1], acc02 + bias[2], acc03 + bias[3]};
    float r1[4] = {acc10 + bias[0], acc11 + bias[1], acc12 + bias[2], acc13 + bias[3]};
    int n0 = nodeBase + nl0;
    if (of32) {
        float* out = (float*)outp;
        if (n0 < NN)
            *(float4*)(out + n0 * DD + obase + o0) = make_float4(r0[0], r0[1], r0[2], r0[3]);
        if (n0 + 1 < NN)
            *(float4*)(out + (n0 + 1) * DD + obase + o0) = make_float4(r1[0], r1[1], r1[2], r1[3]);
    } else {
        unsigned short* out = (unsigned short*)outp;
        if (n0 < NN) {
            unsigned short* op = out + n0 * DD + obase + o0;
            op[0] = f2bf(r0[0]); op[1] = f2bf(r0[1]); op[2] = f2bf(r0[2]); op[3] = f2bf(r0[3]);
        }
        if (n0 + 1 < NN) {
            unsigned short* op = out + (n0 + 1) * DD + obase + o0;
            op[0] = f2bf(r1[0]); op[1] = f2bf(r1[1]); op[2] = f2bf(r1[2]); op[3] = f2bf(r1[3]);
        }
    }
}

extern "C" void kernel_launch(void* const* d_in, const int* in_sizes, int n_in,
                              void* d_out, int out_size, void* d_ws, size_t ws_size,
                              hipStream_t stream) {
    const void* feat = d_in[0];
    const void* src  = d_in[1];
    const void* dst  = d_in[2];
    const void* W    = d_in[3];
    const void* b    = d_in[4];

    // ws layout (bytes): flags[8 int]@0 | deg[50000 int]@32 | norm[50000 f]@200032
    //                    X[6.4M bf16]@400032 | Y[6.4M f32]@13200032  (end ~38.8MB)
    char* wsb = (char*)d_ws;
    int*   flags = (int*)wsb;
    int*   deg   = (int*)(wsb + 32);
    float* norm  = (float*)(wsb + 200032);
    unsigned short* X = (unsigned short*)(wsb + 400032);
    float* Y     = (float*)(wsb + 13200032);

    k_detect<<<1, 256, 0, stream>>>((const int*)src, (const int*)dst,
                                    (const unsigned short*)feat,
                                    (const unsigned short*)W, flags);
    k_zero<<<(NN * DD + 255) / 256, 256, 0, stream>>>(Y, deg);
    k_degree<<<(NE + 255) / 256, 256, 0, stream>>>(dst, deg, flags);
    k_norm<<<(NN + 255) / 256, 256, 0, stream>>>(deg, norm);
    k_prescale<<<(NN * DD / 4 + 255) / 256, 256, 0, stream>>>(feat, norm, X, flags);
    k_scatter<<<NE * 32 / 256, 256, 0, stream>>>(X, src, dst, Y, flags);   // hop 1
    k_mid<<<(NN * DD / 4 + 255) / 256, 256, 0, stream>>>(Y, X, norm);
    k_scatter<<<NE * 32 / 256, 256, 0, stream>>>(X, src, dst, Y, flags);   // hop 2
    dim3 ggrid((NN + TM - 1) / TM, DD / TO);
    k_gemm<<<ggrid, 256, 0, stream>>>(Y, norm, W, b, d_out, flags);
}

// Round 4
// 570.566 us; speedup vs baseline: 10.8470x; 10.8470x over previous
//
#include <hip/hip_runtime.h>
#include <hip/hip_bf16.h>

#define NN 50000
#define NE 1600000
#define DD 128

__device__ __forceinline__ float bf2f(unsigned short u) {
    union { unsigned int i; float f; } c; c.i = ((unsigned int)u) << 16; return c.f;
}
__device__ __forceinline__ unsigned short f2bf(float f) {
    __hip_bfloat16 h = __float2bfloat16(f);
    union { __hip_bfloat16 h; unsigned short u; } c; c.h = h; return c.u;
}
__device__ __forceinline__ int insane_bf16(unsigned short u) {
    unsigned e = (u >> 7) & 0xFF;
    return (e == 0xFF) || (e >= 0x8E);
}

// flags[0]=indices int64; flags[1]=feat f32 (=> out f32); flags[2]=W f32
__global__ void k_detect(const int* __restrict__ srcw, const int* __restrict__ dstw,
                         const unsigned short* __restrict__ feat16,
                         const unsigned short* __restrict__ w16,
                         int* __restrict__ flags) {
    __shared__ int s_idx, s_feat, s_w;
    int tid = threadIdx.x;
    if (tid == 0) { s_idx = 0; s_feat = 0; s_w = 0; }
    __syncthreads();
    if (tid < 64) {
        int v = srcw[2 * tid + 1] | dstw[2 * tid + 1];
        if (v) atomicOr(&s_idx, 1);
    }
    if (insane_bf16(feat16[2 * tid]) || insane_bf16(feat16[2 * tid + 512]))
        atomicOr(&s_feat, 1);
    if (insane_bf16(w16[2 * tid]) || insane_bf16(w16[2 * tid + 512]))
        atomicOr(&s_w, 1);
    __syncthreads();
    if (tid == 0) { flags[0] = (s_idx == 0) ? 1 : 0; flags[1] = s_feat; flags[2] = s_w; }
}

__device__ __forceinline__ int load_idx(const void* p, int e, int is64) {
    long long v = is64 ? ((const long long*)p)[e] : (long long)((const int*)p)[e];
    int i = (int)v;
    return (i < 0) ? 0 : (i >= NN ? NN - 1 : i);
}

__global__ void k_zero(int* __restrict__ deg, int* __restrict__ cnt) {
    int i = blockIdx.x * 256 + threadIdx.x;
    if (i < NN) { deg[i] = 0; cnt[i] = 0; }
}

__global__ void k_degree(const void* __restrict__ dst, int* __restrict__ deg,
                         const int* __restrict__ flags) {
    int e = blockIdx.x * 256 + threadIdx.x;
    if (e >= NE) return;
    atomicAdd(&deg[load_idx(dst, e, flags[0])], 1);
}

__global__ void k_norm(const int* __restrict__ deg, float* __restrict__ norm) {
    int n = blockIdx.x * 256 + threadIdx.x;
    if (n >= NN) return;
    norm[n] = rsqrtf(fmaxf((float)deg[n], 1.0f));
}

// single-workgroup chunked exclusive scan: rowptr[0..NN]
__global__ __launch_bounds__(1024) void k_scan(const int* __restrict__ deg,
                                               int* __restrict__ rowptr) {
    __shared__ int buf[1024];
    __shared__ int carry;
    int tid = threadIdx.x;
    if (tid == 0) carry = 0;
    __syncthreads();
    for (int base = 0; base < NN; base += 1024) {
        int i = base + tid;
        int v = (i < NN) ? deg[i] : 0;
        buf[tid] = v;
        __syncthreads();
        for (int off = 1; off < 1024; off <<= 1) {
            int t = (tid >= off) ? buf[tid - off] : 0;
            __syncthreads();
            buf[tid] += t;
            __syncthreads();
        }
        int incl = buf[tid];
        int total = buf[1023];
        if (i < NN) rowptr[i] = carry + incl - v;
        __syncthreads();
        if (tid == 0) carry += total;
        __syncthreads();
    }
    if (tid == 0) rowptr[NN] = carry;
}

// fill CSR: srclist[rowptr[d] + k] = src of k-th edge into d
__global__ void k_bucket(const void* __restrict__ src, const void* __restrict__ dst,
                         const int* __restrict__ rowptr, int* __restrict__ cnt,
                         int* __restrict__ srclist, const int* __restrict__ flags) {
    int e = blockIdx.x * 256 + threadIdx.x;
    if (e >= NE) return;
    int is64 = flags[0];
    int s = load_idx(src, e, is64);
    int d = load_idx(dst, e, is64);
    int pos = rowptr[d] + atomicAdd(&cnt[d], 1);
    srclist[pos] = s;
}

// X1[n,d] = feat[n,d] * norm[n]  (bf16), 4 elems/thread
__global__ void k_prescale(const void* __restrict__ feat,
                           const float* __restrict__ norm,
                           unsigned short* __restrict__ X,
                           const int* __restrict__ flags) {
    int i = blockIdx.x * 256 + threadIdx.x;
    if (i >= NN * DD / 4) return;
    float nm = norm[i >> 5];
    float4 v;
    if (flags[1]) {
        v = ((const float4*)feat)[i];
    } else {
        ushort4 f = ((const ushort4*)feat)[i];
        v.x = bf2f(f.x); v.y = bf2f(f.y); v.z = bf2f(f.z); v.w = bf2f(f.w);
    }
    ushort4 o;
    o.x = f2bf(v.x * nm); o.y = f2bf(v.y * nm);
    o.z = f2bf(v.z * nm); o.w = f2bf(v.w * nm);
    ((ushort4*)X)[i] = o;
}

// gather-reduce: one wave per dst node; lane owns cols 2l,2l+1.
// mode 0: out16 = bf16(acc * norm[n]^2)   (hop1 -> X2)
// mode 1: out = acc  (f32 if of32 else bf16) into d_out  (hop2 -> Y)
__global__ __launch_bounds__(256) void k_gather(const unsigned short* __restrict__ Xin,
        const int* __restrict__ rowptr, const int* __restrict__ srclist,
        const float* __restrict__ norm, void* __restrict__ outp,
        const int* __restrict__ flags, int mode) {
    int wid = (blockIdx.x * 256 + threadIdx.x) >> 6;
    int lane = threadIdx.x & 63;
    if (wid >= NN) return;
    int beg = rowptr[wid], end = rowptr[wid + 1];
    float a0 = 0.f, a1 = 0.f;
    int j = beg;
    for (; j + 4 <= end; j += 4) {
        int s0 = srclist[j + 0], s1 = srclist[j + 1];
        int s2 = srclist[j + 2], s3 = srclist[j + 3];
        unsigned v0 = *(const unsigned*)(Xin + s0 * DD + 2 * lane);
        unsigned v1 = *(const unsigned*)(Xin + s1 * DD + 2 * lane);
        unsigned v2 = *(const unsigned*)(Xin + s2 * DD + 2 * lane);
        unsigned v3 = *(const unsigned*)(Xin + s3 * DD + 2 * lane);
        a0 += bf2f((unsigned short)(v0 & 0xffff)); a1 += bf2f((unsigned short)(v0 >> 16));
        a0 += bf2f((unsigned short)(v1 & 0xffff)); a1 += bf2f((unsigned short)(v1 >> 16));
        a0 += bf2f((unsigned short)(v2 & 0xffff)); a1 += bf2f((unsigned short)(v2 >> 16));
        a0 += bf2f((unsigned short)(v3 & 0xffff)); a1 += bf2f((unsigned short)(v3 >> 16));
    }
    for (; j < end; ++j) {
        int s = srclist[j];
        unsigned v = *(const unsigned*)(Xin + s * DD + 2 * lane);
        a0 += bf2f((unsigned short)(v & 0xffff)); a1 += bf2f((unsigned short)(v >> 16));
    }
    if (mode == 0) {
        float nm = norm[wid]; float n2 = nm * nm;
        unsigned short lo = f2bf(a0 * n2), hi = f2bf(a1 * n2);
        *(unsigned*)((unsigned short*)outp + wid * DD + 2 * lane)
            = ((unsigned)hi << 16) | (unsigned)lo;
    } else {
        if (flags[1]) {
            *(float2*)((float*)outp + wid * DD + 2 * lane) = make_float2(a0, a1);
        } else {
            unsigned short lo = f2bf(a0), hi = f2bf(a1);
            *(unsigned*)((unsigned short*)outp + wid * DD + 2 * lane)
                = ((unsigned)hi << 16) | (unsigned)lo;
        }
    }
}

// In-place GEMM on d_out: out[n,:] = (Y[n,:]*norm[n]) @ W^T + b
// TM=32 nodes/block, all 128 outs per block (no inter-block row sharing).
// W in LDS as packed-bf16 dwords uw[o*65 + kk]; thread outs o = og + 16j.
__global__ __launch_bounds__(256) void k_gemm(void* __restrict__ Yio,
        const float* __restrict__ norm, const void* __restrict__ Wp,
        const void* __restrict__ bp, const int* __restrict__ flags) {
    __shared__ unsigned int uw[DD * 65];     // 33,280 B
    __shared__ float Fl[32 * 130];           // 16,640 B
    int tid = threadIdx.x;
    int nodeBase = blockIdx.x * 32;
    int wf32 = flags[2];
    int of32 = flags[1];

    // stage W (packed bf16 pairs along k)
    for (int idx = tid; idx < DD * 64; idx += 256) {
        int o = idx >> 6, kk = idx & 63;
        unsigned pk;
        if (wf32) {
            float2 w = ((const float2*)Wp)[o * 64 + kk];
            pk = ((unsigned)f2bf(w.y) << 16) | (unsigned)f2bf(w.x);
        } else {
            pk = ((const unsigned*)Wp)[o * 64 + kk];
        }
        uw[o * 65 + kk] = pk;
    }
    // stage Y rows * norm
    for (int idx = tid; idx < 32 * DD; idx += 256) {
        int nl = idx >> 7, d = idx & 127;
        int n = nodeBase + nl;
        float v = 0.0f;
        if (n < NN) {
            float nm = norm[n];
            v = of32 ? ((const float*)Yio)[n * DD + d] * nm
                     : bf2f(((const unsigned short*)Yio)[n * DD + d]) * nm;
        }
        Fl[nl * 130 + d] = v;
    }
    __syncthreads();

    int og = tid & 15;           // out group: o = og + 16*j
    int ng = tid >> 4;           // node group: nodes 2*ng, 2*ng+1
    int nl0 = ng * 2;
    float acc0[8], acc1[8];
    #pragma unroll
    for (int j = 0; j < 8; ++j) { acc0[j] = 0.f; acc1[j] = 0.f; }
    const float* r0 = &Fl[nl0 * 130];
    const float* r1 = &Fl[(nl0 + 1) * 130];
    #pragma unroll 4
    for (int kk = 0; kk < 64; ++kk) {
        float2 f0 = *(const float2*)(r0 + 2 * kk);
        float2 f1 = *(const float2*)(r1 + 2 * kk);
        #pragma unroll
        for (int j = 0; j < 8; ++j) {
            unsigned w = uw[(og + 16 * j) * 65 + kk];
            float w0 = bf2f((unsigned short)(w & 0xffff));
            float w1 = bf2f((unsigned short)(w >> 16));
            acc0[j] += f0.x * w0 + f0.y * w1;
            acc1[j] += f1.x * w0 + f1.y * w1;
        }
    }
    int n0 = nodeBase + nl0;
    #pragma unroll
    for (int j = 0; j < 8; ++j) {
        int o = og + 16 * j;
        float bias = wf32 ? ((const float*)bp)[o] : bf2f(((const unsigned short*)bp)[o]);
        float v0 = acc0[j] + bias, v1 = acc1[j] + bias;
        if (of32) {
            float* out = (float*)Yio;
            if (n0 < NN)     out[n0 * DD + o] = v0;
            if (n0 + 1 < NN) out[(n0 + 1) * DD + o] = v1;
        } else {
            unsigned short* out = (unsigned short*)Yio;
            if (n0 < NN)     out[n0 * DD + o] = f2bf(v0);
            if (n0 + 1 < NN) out[(n0 + 1) * DD + o] = f2bf(v1);
        }
    }
}

extern "C" void kernel_launch(void* const* d_in, const int* in_sizes, int n_in,
                              void* d_out, int out_size, void* d_ws, size_t ws_size,
                              hipStream_t stream) {
    const void* feat = d_in[0];
    const void* src  = d_in[1];
    const void* dst  = d_in[2];
    const void* W    = d_in[3];
    const void* b    = d_in[4];

    // ws layout (bytes): flags@0 | deg@32 | cnt@200032 | rowptr@400032 |
    //   norm@600064 | srclist@800064 | X1@7200064 | X2@20000064  (end 32.8MB)
    char* wsb = (char*)d_ws;
    int*   flags   = (int*)wsb;
    int*   deg     = (int*)(wsb + 32);
    int*   cnt     = (int*)(wsb + 200032);
    int*   rowptr  = (int*)(wsb + 400032);
    float* norm    = (float*)(wsb + 600064);
    int*   srclist = (int*)(wsb + 800064);
    unsigned short* X1 = (unsigned short*)(wsb + 7200064);
    unsigned short* X2 = (unsigned short*)(wsb + 20000064);

    k_detect<<<1, 256, 0, stream>>>((const int*)src, (const int*)dst,
                                    (const unsigned short*)feat,
                                    (const unsigned short*)W, flags);
    k_zero<<<(NN + 255) / 256, 256, 0, stream>>>(deg, cnt);
    k_degree<<<(NE + 255) / 256, 256, 0, stream>>>(dst, deg, flags);
    k_norm<<<(NN + 255) / 256, 256, 0, stream>>>(deg, norm);
    k_scan<<<1, 1024, 0, stream>>>(deg, rowptr);
    k_bucket<<<(NE + 255) / 256, 256, 0, stream>>>(src, dst, rowptr, cnt, srclist, flags);
    k_prescale<<<(NN * DD / 4 + 255) / 256, 256, 0, stream>>>(feat, norm, X1, flags);
    k_gather<<<(NN + 3) / 4, 256, 0, stream>>>(X1, rowptr, srclist, norm, X2, flags, 0);
    k_gather<<<(NN + 3) / 4, 256, 0, stream>>>(X2, rowptr, srclist, norm, d_out, flags, 1);
    k_gemm<<<(NN + 31) / 32, 256, 0, stream>>>(d_out, norm, W, b, flags);
}